// Round 9
// baseline (1063.670 us; speedup 1.0000x reference)
//
#include <hip/hip_runtime.h>
#include <hip/hip_bf16.h>

typedef unsigned int uint;
typedef unsigned short ushort;
typedef short bf16x8 __attribute__((ext_vector_type(8)));
typedef ushort u16x8 __attribute__((ext_vector_type(8)));
typedef float f32x4 __attribute__((ext_vector_type(4)));

#define B_ 16
#define C_ 256
#define O_ 256
#define HW_ 4096
#define KK_ 2304   // 9 * 256, tap-major: k = tap*256 + c
#define HP_ 66     // halo-padded spatial dim

#define VMW(n) asm volatile("s_waitcnt vmcnt(" #n ")" ::: "memory")
#define LGW(n) asm volatile("s_waitcnt lgkmcnt(" #n ")" ::: "memory")
#define SB0 __builtin_amdgcn_sched_barrier(0)
#define PRIO1 __builtin_amdgcn_s_setprio(1)
#define PRIO0 __builtin_amdgcn_s_setprio(0)
#define BAR __builtin_amdgcn_s_barrier()

__device__ __forceinline__ ushort f2bf(float f) {
    uint u = __builtin_bit_cast(uint, f);
    uint r = (u + 0x7FFFu + ((u >> 16) & 1u)) >> 16;   // RNE
    return (ushort)r;
}

// async global->LDS, 16B per lane; LDS dest is wave-uniform base + lane*16
__device__ __forceinline__ void gl16(const ushort* g, ushort* l) {
    __builtin_amdgcn_global_load_lds(
        (const __attribute__((address_space(1))) void*)g,
        (__attribute__((address_space(3))) void*)l,
        16, 0, 0);
}

// ---------------- kernel 1: NCHW f32 -> padded NHWC bf16 + pool partials + halo ------
__global__ __launch_bounds__(256) void transpose_kernel(const float* __restrict__ x,
                                                        ushort* __restrict__ xT,
                                                        float* __restrict__ part) {
    __shared__ ushort tl[64][264];   // [w][c], pad 8 -> row stride 528B
    const int h = blockIdx.x, b = blockIdx.y;
    const int c = threadIdx.x;
    const float* src = x + (((size_t)(b * C_ + c)) * 64 + h) * 64;   // x[b][c][h][*]
    float s = 0.0f;
    #pragma unroll
    for (int j = 0; j < 16; ++j) {
        float4 v = ((const float4*)src)[j];
        s += v.x + v.y + v.z + v.w;
        tl[j * 4 + 0][c] = f2bf(v.x);
        tl[j * 4 + 1][c] = f2bf(v.y);
        tl[j * 4 + 2][c] = f2bf(v.z);
        tl[j * 4 + 3][c] = f2bf(v.w);
    }
    part[(b * C_ + c) * 64 + h] = s;
    // zero 5 halo pixels per block (260 total per sample, 64 blocks x 5 = 320 >= 260)
    ushort* xbs = xT + (size_t)b * HP_ * HP_ * C_;
    #pragma unroll
    for (int t = 0; t < 5; ++t) {
        int i = h * 5 + t;
        if (i < 260) {
            int hp, wp;
            if (i < 66)       { hp = 0;       wp = i;       }
            else if (i < 132) { hp = 65;      wp = i - 66;  }
            else if (i < 196) { hp = i - 131; wp = 0;       }
            else              { hp = i - 195; wp = 65;      }
            xbs[((size_t)hp * HP_ + wp) * C_ + c] = 0;
        }
    }
    __syncthreads();
    const int cw = threadIdx.x & 31, rw = threadIdx.x >> 5;
    ushort* dstrow = xT + (((size_t)(b * HP_) + h + 1) * HP_ + 1) * C_;  // xT[b][h+1][1][0]
    #pragma unroll
    for (int j = 0; j < 8; ++j) {
        int w = rw + 8 * j;
        *(u16x8*)(dstrow + (size_t)w * C_ + cw * 8) = *(const u16x8*)&tl[w][cw * 8];
    }
}

// ---------------- kernel 2: pooled reduce + gating softmax ----------------
__global__ __launch_bounds__(256) void gate_kernel(const float* __restrict__ part,
                                                   const float* __restrict__ gw,
                                                   float* __restrict__ gates) {
    const int b = blockIdx.x, c = threadIdx.x;
    const float4* pp = (const float4*)(part + (size_t)(b * C_ + c) * 64);
    float p = 0.0f;
    #pragma unroll
    for (int j = 0; j < 16; ++j) { float4 v = pp[j]; p += v.x + v.y + v.z + v.w; }
    p *= (1.0f / 4096.0f);
    float l0 = p * gw[0 * C_ + c], l1 = p * gw[1 * C_ + c];
    float l2 = p * gw[2 * C_ + c], l3 = p * gw[3 * C_ + c];
    #pragma unroll
    for (int off = 32; off; off >>= 1) {
        l0 += __shfl_down(l0, off); l1 += __shfl_down(l1, off);
        l2 += __shfl_down(l2, off); l3 += __shfl_down(l3, off);
    }
    __shared__ float red[4][4];
    const int wid = c >> 6, lane = c & 63;
    if (lane == 0) { red[wid][0] = l0; red[wid][1] = l1; red[wid][2] = l2; red[wid][3] = l3; }
    __syncthreads();
    if (c < 4) {
        float logit = red[0][c] + red[1][c] + red[2][c] + red[3][c];
        float m = logit;
        m = fmaxf(m, __shfl_xor(m, 1)); m = fmaxf(m, __shfl_xor(m, 2));
        float ex = expf(logit - m);
        float ssum = ex; ssum += __shfl_xor(ssum, 1); ssum += __shfl_xor(ssum, 2);
        gates[b * 4 + c] = ex / ssum;
    }
}

// ---------------- kernel 3: combine expert weights (tap-major k) ----------------
__global__ __launch_bounds__(256) void combine_kernel(const float* __restrict__ We,
                                                      const float* __restrict__ gates,
                                                      ushort* __restrict__ Wc) {
    const int o = blockIdx.x, c = threadIdx.x;
    __shared__ float g[64];
    if (c < 64) g[c] = gates[c];
    __syncthreads();
    float w[4][9];
    #pragma unroll
    for (int e = 0; e < 4; ++e) {
        const float* p = We + (((size_t)e * O_ + o) * C_ + c) * 9;
        #pragma unroll
        for (int tap = 0; tap < 9; ++tap) w[e][tap] = p[tap];
    }
    #pragma unroll
    for (int b = 0; b < B_; ++b) {
        float g0 = g[b*4+0], g1 = g[b*4+1], g2 = g[b*4+2], g3 = g[b*4+3];
        #pragma unroll
        for (int tap = 0; tap < 9; ++tap) {
            float v = g0*w[0][tap] + g1*w[1][tap] + g2*w[2][tap] + g3*w[3][tap];
            Wc[((size_t)(b * O_ + o)) * KK_ + tap * C_ + c] = f2bf(v);
        }
    }
}

// ---------------- kernel 4: 256x256 conv GEMM; A via LDS ring, B direct-to-reg ------
// grid = 256 blocks (16 n-tiles x 16 samples) = 1/CU, 512 threads (8 waves, 2M x 4N).
// 36 K-tiles of BK=64 (tap-uniform). A: 3-slot LDS ring (96KB), gl16 DMA, depth-2
// prefetch, R7's 0-conflict 128B-row XOR swizzle. B: loaded DIRECTLY into MFMA
// fragment registers from NHWC xT (per-lane contiguous 16B), double-buffered.
// Per tile: ONE barrier + ONE counted vmcnt(12) (stage t+2 / B t+1 stay in flight).
__global__ __launch_bounds__(512, 2) void conv_kernel(const ushort* __restrict__ xT,
                                                      const ushort* __restrict__ Wc,
                                                      float* __restrict__ out) {
    __shared__ ushort As[3][256][64];   // [slot][o][k]  128B rows, linear DMA dest

    // bijective XCD chunk swizzle: 32 consecutive wgids per XCD (2 samples/XCD)
    const int d = blockIdx.x;
    const int wgid = (d & 7) * 32 + (d >> 3);
    const int b  = wgid >> 4;
    const int n0 = (wgid & 15) * 256;

    const int tid = threadIdx.x;
    const int wid = tid >> 6, lane = tid & 63;
    const int lr = lane & 15, lg = lane >> 4;
    const int wro = (wid >> 2) * 128;           // wave M-offset (o)
    const int wco = (wid & 3) * 64;             // wave N-offset (px)

    // A staging roles (R7 geometry): wave stages rows [32*wid, 32*wid+32), 4 gl16
    const int srow = lane >> 3;                 // 0..7
    const int sgr  = (lane & 7) ^ srow;         // source granule (XOR swizzle)
    const ushort* aS = Wc + ((size_t)(b * O_ + wid * 32 + srow)) * KK_ + sgr * 8;
    const ushort* xb = xT + (size_t)b * HP_ * HP_ * C_;

    // B per-lane voffsets: wave's 64 px = one image row; pixel = n0+wco+nn*16+lr
    const int hh = (n0 >> 6) + (wco >> 6);      // uniform per wave
    int voffB[4];
    #pragma unroll
    for (int nn = 0; nn < 4; ++nn)
        voffB[nn] = ((hh + 1) * HP_ + (nn * 16 + lr + 1)) * C_ + lg * 8;

    f32x4 acc[8][4];
    #pragma unroll
    for (int i = 0; i < 8; ++i)
        #pragma unroll
        for (int j = 0; j < 4; ++j) acc[i][j] = (f32x4){0.f, 0.f, 0.f, 0.f};

    auto stageA = [&](int ss, int t) {
        #pragma unroll
        for (int i = 0; i < 4; ++i)
            gl16(aS + (size_t)t * 64 + i * 8 * KK_, &As[ss][wid * 32 + i * 8][0]);
    };
    // B fragments direct from global: dst[ks*4+nn], ks = k-sub (32), nn = n-block
    auto loadB = [&](bf16x8* dst, int t) {
        const int tap = t >> 2, c0 = (t & 3) * 64;
        const int t3 = (tap * 11) >> 5;          // tap/3
        const ushort* p0 = xb + ((t3 - 1) * HP_ + (tap - 3 * t3 - 1)) * C_ + c0;
        #pragma unroll
        for (int ks = 0; ks < 2; ++ks)
            #pragma unroll
            for (int nn = 0; nn < 4; ++nn)
                dst[ks * 4 + nn] = *(const bf16x8*)(p0 + ks * 32 + voffB[nn]);
    };

    bf16x8 aF1[4], aF2[4], aF3[4], aF4[4], bS0[8], bS1[8];

    auto dsA = [&](int s, int half, int ksub, bf16x8* dst) {
        #pragma unroll
        for (int m = 0; m < 4; ++m)
            dst[m] = *(const bf16x8*)
                &As[s][wro + half * 64 + m * 16 + lr][(((ksub << 2) | lg) ^ (lr & 7)) * 8];
    };
    auto mfma16 = [&](int ao, bf16x8* a, bf16x8* bv) {
        #pragma unroll
        for (int m = 0; m < 4; ++m)
            #pragma unroll
            for (int n = 0; n < 4; ++n)
                acc[ao + m][n] = __builtin_amdgcn_mfma_f32_16x16x32_bf16(a[m], bv[n], acc[ao + m][n], 0, 0, 0);
    };

#define TILE(SL, SN, SS, T, BUSE, BNXT, DOSTG, DOLDB, VMWAIT, DONEXT)          \
    {                                                                          \
        if (DOSTG) stageA(SS, (T) + 2);                                        \
        if (DOLDB) loadB(BNXT, (T) + 1);                                       \
        dsA(SL, 1, 0, aF2);                                                    \
        VMWAIT; SB0;                                                           \
        LGW(4); SB0;                                                           \
        PRIO1; mfma16(0, aF1, BUSE + 0); PRIO0;                                \
        dsA(SL, 0, 1, aF3);                                                    \
        LGW(4); SB0;                                                           \
        PRIO1; mfma16(4, aF2, BUSE + 0); PRIO0;                                \
        dsA(SL, 1, 1, aF4);                                                    \
        LGW(4); SB0;                                                           \
        PRIO1; mfma16(0, aF3, BUSE + 4); PRIO0;                                \
        LGW(0); SB0;                                                           \
        PRIO1; mfma16(4, aF4, BUSE + 4); PRIO0;                                \
        if (DONEXT) { BAR; dsA(SN, 0, 0, aF1); }                               \
    }

    // prologue: stage tiles 0,1; load B(0); wait tile-0 A only (counted); pre-read
    stageA(0, 0); stageA(1, 1);
    loadB(bS0, 0);
    VMW(12);                       // stage(0) done; stage(1)+B(0) in flight
    BAR;
    dsA(0, 0, 0, aF1);

    #pragma unroll 1
    for (int t = 0; t < 34; ++t) {
        const int sl = t % 3, sn = (t + 1) % 3, ss = (t + 2) % 3;
        if (t & 1) TILE(sl, sn, ss, t, bS1, bS0, 1, 1, VMW(12), 1)
        else       TILE(sl, sn, ss, t, bS0, bS1, 1, 1, VMW(12), 1)
    }
    // t=34 (slot 1): no stage(36); B(35) -> bS1; counted vmcnt(8)
    TILE(1, 2, 0, 34, bS0, bS1, 0, 1, VMW(8), 1)
    // t=35 (slot 2): final; drain
    TILE(2, 0, 0, 35, bS1, bS0, 0, 0, VMW(0), 0)
#undef TILE

    // epilogue: C/D layout col=lane&15, row=(lane>>4)*4+j
    #pragma unroll
    for (int m = 0; m < 8; ++m)
        #pragma unroll
        for (int n = 0; n < 4; ++n)
            #pragma unroll
            for (int j = 0; j < 4; ++j) {
                int ro = wro + m * 16 + lg * 4 + j;
                int co = n0 + wco + n * 16 + lr;
                out[((size_t)(b * O_ + ro)) * HW_ + co] = acc[m][n][j];
            }
}

extern "C" void kernel_launch(void* const* d_in, const int* in_sizes, int n_in,
                              void* d_out, int out_size, void* d_ws, size_t ws_size,
                              hipStream_t stream) {
    const float* x  = (const float*)d_in[0];
    const float* We = (const float*)d_in[1];
    const float* gw = (const float*)d_in[2];
    float* out = (float*)d_out;

    // ws: part @0 (256KB), gates @262144, Wc @263168 (18.87MB -> 19137536),
    //     xT @19137536 (16*66*66*256*2B = 35.68MB) -> ~54.8MB total
    float*  part  = (float*)d_ws;
    float*  gates = (float*)((char*)d_ws + 262144);
    ushort* Wcomb = (ushort*)((char*)d_ws + 263168);
    ushort* xTp   = (ushort*)((char*)d_ws + 19137536);

    transpose_kernel<<<dim3(64, 16), 256, 0, stream>>>(x, xTp, part);
    gate_kernel<<<16, 256, 0, stream>>>(part, gw, gates);
    combine_kernel<<<O_, 256, 0, stream>>>(We, gates, Wcomb);
    conv_kernel<<<256, 512, 0, stream>>>(xTp, Wcomb, out);
}

// Round 10
// 126.389 us; speedup vs baseline: 8.4158x; 8.4158x over previous
//
#include <hip/hip_runtime.h>
#include <hip/hip_bf16.h>

typedef unsigned int uint;
typedef unsigned short ushort;
typedef short bf16x8 __attribute__((ext_vector_type(8)));
typedef ushort u16x8 __attribute__((ext_vector_type(8)));
typedef float f32x4 __attribute__((ext_vector_type(4)));

#define B_ 16
#define C_ 256
#define O_ 256
#define HW_ 4096
#define KK_ 2304   // 9 * 256, tap-major: k = tap*256 + c
#define HP_ 66     // halo-padded spatial dim

#define VMW(n) asm volatile("s_waitcnt vmcnt(" #n ")" ::: "memory")
#define LGW(n) asm volatile("s_waitcnt lgkmcnt(" #n ")" ::: "memory")
#define SB0 __builtin_amdgcn_sched_barrier(0)
#define PRIO1 __builtin_amdgcn_s_setprio(1)
#define PRIO0 __builtin_amdgcn_s_setprio(0)
#define BAR __builtin_amdgcn_s_barrier()

__device__ __forceinline__ ushort f2bf(float f) {
    uint u = __builtin_bit_cast(uint, f);
    uint r = (u + 0x7FFFu + ((u >> 16) & 1u)) >> 16;   // RNE
    return (ushort)r;
}

// async global->LDS, 16B per lane; LDS dest is wave-uniform base + lane*16
__device__ __forceinline__ void gl16(const ushort* g, ushort* l) {
    __builtin_amdgcn_global_load_lds(
        (const __attribute__((address_space(1))) void*)g,
        (__attribute__((address_space(3))) void*)l,
        16, 0, 0);
}

// ---------------- kernel 1: NCHW f32 -> padded NHWC bf16 + pool partials + halo ------
__global__ __launch_bounds__(256) void transpose_kernel(const float* __restrict__ x,
                                                        ushort* __restrict__ xT,
                                                        float* __restrict__ part) {
    __shared__ ushort tl[64][264];   // [w][c], pad 8 -> row stride 528B
    const int h = blockIdx.x, b = blockIdx.y;
    const int c = threadIdx.x;
    const float* src = x + (((size_t)(b * C_ + c)) * 64 + h) * 64;   // x[b][c][h][*]
    float s = 0.0f;
    #pragma unroll
    for (int j = 0; j < 16; ++j) {
        float4 v = ((const float4*)src)[j];
        s += v.x + v.y + v.z + v.w;
        tl[j * 4 + 0][c] = f2bf(v.x);
        tl[j * 4 + 1][c] = f2bf(v.y);
        tl[j * 4 + 2][c] = f2bf(v.z);
        tl[j * 4 + 3][c] = f2bf(v.w);
    }
    part[(b * C_ + c) * 64 + h] = s;
    // zero 5 halo pixels per block (260 total per sample, 64 blocks x 5 = 320 >= 260)
    ushort* xbs = xT + (size_t)b * HP_ * HP_ * C_;
    #pragma unroll
    for (int t = 0; t < 5; ++t) {
        int i = h * 5 + t;
        if (i < 260) {
            int hp, wp;
            if (i < 66)       { hp = 0;       wp = i;       }
            else if (i < 132) { hp = 65;      wp = i - 66;  }
            else if (i < 196) { hp = i - 131; wp = 0;       }
            else              { hp = i - 195; wp = 65;      }
            xbs[((size_t)hp * HP_ + wp) * C_ + c] = 0;
        }
    }
    __syncthreads();
    const int cw = threadIdx.x & 31, rw = threadIdx.x >> 5;
    ushort* dstrow = xT + (((size_t)(b * HP_) + h + 1) * HP_ + 1) * C_;  // xT[b][h+1][1][0]
    #pragma unroll
    for (int j = 0; j < 8; ++j) {
        int w = rw + 8 * j;
        *(u16x8*)(dstrow + (size_t)w * C_ + cw * 8) = *(const u16x8*)&tl[w][cw * 8];
    }
}

// ---------------- kernel 2: pooled reduce + gating softmax ----------------
__global__ __launch_bounds__(256) void gate_kernel(const float* __restrict__ part,
                                                   const float* __restrict__ gw,
                                                   float* __restrict__ gates) {
    const int b = blockIdx.x, c = threadIdx.x;
    const float4* pp = (const float4*)(part + (size_t)(b * C_ + c) * 64);
    float p = 0.0f;
    #pragma unroll
    for (int j = 0; j < 16; ++j) { float4 v = pp[j]; p += v.x + v.y + v.z + v.w; }
    p *= (1.0f / 4096.0f);
    float l0 = p * gw[0 * C_ + c], l1 = p * gw[1 * C_ + c];
    float l2 = p * gw[2 * C_ + c], l3 = p * gw[3 * C_ + c];
    #pragma unroll
    for (int off = 32; off; off >>= 1) {
        l0 += __shfl_down(l0, off); l1 += __shfl_down(l1, off);
        l2 += __shfl_down(l2, off); l3 += __shfl_down(l3, off);
    }
    __shared__ float red[4][4];
    const int wid = c >> 6, lane = c & 63;
    if (lane == 0) { red[wid][0] = l0; red[wid][1] = l1; red[wid][2] = l2; red[wid][3] = l3; }
    __syncthreads();
    if (c < 4) {
        float logit = red[0][c] + red[1][c] + red[2][c] + red[3][c];
        float m = logit;
        m = fmaxf(m, __shfl_xor(m, 1)); m = fmaxf(m, __shfl_xor(m, 2));
        float ex = expf(logit - m);
        float ssum = ex; ssum += __shfl_xor(ssum, 1); ssum += __shfl_xor(ssum, 2);
        gates[b * 4 + c] = ex / ssum;
    }
}

// ---------------- kernel 3: combine expert weights (tap-major k) ----------------
__global__ __launch_bounds__(256) void combine_kernel(const float* __restrict__ We,
                                                      const float* __restrict__ gates,
                                                      ushort* __restrict__ Wc) {
    const int o = blockIdx.x, c = threadIdx.x;
    __shared__ float g[64];
    if (c < 64) g[c] = gates[c];
    __syncthreads();
    float w[4][9];
    #pragma unroll
    for (int e = 0; e < 4; ++e) {
        const float* p = We + (((size_t)e * O_ + o) * C_ + c) * 9;
        #pragma unroll
        for (int tap = 0; tap < 9; ++tap) w[e][tap] = p[tap];
    }
    #pragma unroll
    for (int b = 0; b < B_; ++b) {
        float g0 = g[b*4+0], g1 = g[b*4+1], g2 = g[b*4+2], g3 = g[b*4+3];
        #pragma unroll
        for (int tap = 0; tap < 9; ++tap) {
            float v = g0*w[0][tap] + g1*w[1][tap] + g2*w[2][tap] + g3*w[3][tap];
            Wc[((size_t)(b * O_ + o)) * KK_ + tap * C_ + c] = f2bf(v);
        }
    }
}

// ---------------- kernel 4: 256x256 conv GEMM; A via LDS ring, B direct-to-reg ------
// grid = 256 blocks (16 n-tiles x 16 samples) = 1/CU, 512 threads (8 waves, 2M x 4N).
// 36 K-tiles of BK=64. A: 3-slot LDS ring (96KB), gl16 DMA, depth-2 prefetch, R7's
// 0-conflict 128B-row XOR swizzle, aF ping-pong (2 arrays). B: per-k-sub fragments
// loaded DIRECTLY to registers from NHWC xT (bK0/bK1, 32 VGPR total). Per tile:
// ONE barrier + two counted VMW(8) (stage t+2 / Bk0(t+1) always stay in flight).
// Register budget: acc 128 AGPR + ~95 VGPR -> no spills (R9's failure mode).
__global__ __launch_bounds__(512, 2) void conv_kernel(const ushort* __restrict__ xT,
                                                      const ushort* __restrict__ Wc,
                                                      float* __restrict__ out) {
    __shared__ ushort As[3][256][64];   // [slot][o][k]  128B rows, linear DMA dest

    // bijective XCD chunk swizzle: 32 consecutive wgids per XCD (2 samples/XCD)
    const int d = blockIdx.x;
    const int wgid = (d & 7) * 32 + (d >> 3);
    const int b  = wgid >> 4;
    const int n0 = (wgid & 15) * 256;

    const int tid = threadIdx.x;
    const int wid = tid >> 6, lane = tid & 63;
    const int lr = lane & 15, lg = lane >> 4;
    const int wro = (wid >> 2) * 128;           // wave M-offset (o)
    const int wco = (wid & 3) * 64;             // wave N-offset (px)

    // A staging roles (R7 geometry): wave stages rows [32*wid, 32*wid+32), 4 gl16
    const int srow = lane >> 3;                 // 0..7
    const int sgr  = (lane & 7) ^ srow;         // source granule (XOR swizzle)
    const ushort* aS = Wc + ((size_t)(b * O_ + wid * 32 + srow)) * KK_ + sgr * 8;
    const ushort* xb = xT + (size_t)b * HP_ * HP_ * C_;

    // B per-lane voffsets: wave's 64 px = one image row; pixel = n0+wco+nn*16+lr
    const int hh = (n0 >> 6) + (wco >> 6);      // uniform per wave
    int voffB[4];
    #pragma unroll
    for (int nn = 0; nn < 4; ++nn)
        voffB[nn] = ((hh + 1) * HP_ + (nn * 16 + lr + 1)) * C_ + lg * 8;

    f32x4 acc[8][4];
    #pragma unroll
    for (int i = 0; i < 8; ++i)
        #pragma unroll
        for (int j = 0; j < 4; ++j) acc[i][j] = (f32x4){0.f, 0.f, 0.f, 0.f};

    auto stageA = [&](int ss, int t) {
        #pragma unroll
        for (int i = 0; i < 4; ++i)
            gl16(aS + (size_t)t * 64 + i * 8 * KK_, &As[ss][wid * 32 + i * 8][0]);
    };
    // B k-sub fragment direct from global: dst[nn], 4x global_load_dwordx4
    auto loadBk = [&](bf16x8* dst, int t, int ks) {
        const int tap = t >> 2, c0 = (t & 3) * 64;
        const int t3 = (tap * 11) >> 5;          // tap/3
        const int toff = ((t3 - 1) * HP_ + (tap - 3 * t3 - 1)) * C_ + c0 + ks * 32;
        #pragma unroll
        for (int nn = 0; nn < 4; ++nn)
            dst[nn] = *(const bf16x8*)(xb + (toff + voffB[nn]));
    };

    bf16x8 aF1[4], aF2[4], bK0[4], bK1[4];

    auto dsA = [&](int s, int half, int ksub, bf16x8* dst) {
        #pragma unroll
        for (int m = 0; m < 4; ++m)
            dst[m] = *(const bf16x8*)
                &As[s][wro + half * 64 + m * 16 + lr][(((ksub << 2) | lg) ^ (lr & 7)) * 8];
    };
    auto mfma16 = [&](int ao, bf16x8* a, bf16x8* bv) {
        #pragma unroll
        for (int m = 0; m < 4; ++m)
            #pragma unroll
            for (int n = 0; n < 4; ++n)
                acc[ao + m][n] = __builtin_amdgcn_mfma_f32_16x16x32_bf16(a[m], bv[n], acc[ao + m][n], 0, 0, 0);
    };

    // prologue: vm FIFO = [stgA(0), stgA(1), Bk0(0)]
    stageA(0, 0); stageA(1, 1);
    loadBk(bK0, 0, 0);
    VMW(8);                        // stgA(0) landed; [stgA(1), Bk0(0)] in flight
    BAR;
    dsA(0, 0, 0, aF1);

    // steady state invariant entering tile t: vm outstanding = [stgA(t+1), Bk0(t)]
    #pragma unroll 1
    for (int t = 0; t < 34; ++t) {
        const int s = t % 3, sn = (t + 1) % 3, ss = (t + 2) % 3;
        loadBk(bK1, t, 1);                        // +4  (older than stage)
        stageA(ss, t + 2);                        // +4
        dsA(s, 1, 0, aF2);
        VMW(8); SB0;                              // Bk0(t) + stgA(t+1) done
        LGW(4); SB0;                              // aF1 (h0,k0) ready
        PRIO1; mfma16(0, aF1, bK0); PRIO0;
        dsA(s, 0, 1, aF1);
        LGW(4); SB0;                              // aF2 (h1,k0) ready
        PRIO1; mfma16(4, aF2, bK0); PRIO0;
        loadBk(bK0, t + 1, 0);                    // +4 (bK0 regs free after issue above)
        dsA(s, 1, 1, aF2);
        VMW(8); SB0;                              // Bk1(t) done; [stgA(t+2), Bk0(t+1)] fly
        LGW(4); SB0;                              // aF1 (h0,k1) ready
        PRIO1; mfma16(0, aF1, bK1); PRIO0;
        LGW(0); SB0;                              // aF2 (h1,k1) ready
        PRIO1; mfma16(4, aF2, bK1); PRIO0;
        BAR;                                      // all waves: slot sn staged, slot s drained
        dsA(sn, 0, 0, aF1);                       // pre-read next tile (h0,k0)
    }
    // t=34 (slot 1): no stageA(36). entering: [stgA(35), Bk0(34)]
    {
        loadBk(bK1, 34, 1);
        dsA(1, 1, 0, aF2);
        VMW(4); SB0;                              // Bk0(34) done (stgA(35) also drains)
        LGW(4); SB0;
        PRIO1; mfma16(0, aF1, bK0); PRIO0;
        dsA(1, 0, 1, aF1);
        LGW(4); SB0;
        PRIO1; mfma16(4, aF2, bK0); PRIO0;
        loadBk(bK0, 35, 0);
        dsA(1, 1, 1, aF2);
        VMW(4); SB0;                              // Bk1(34) done; [Bk0(35)] in flight
        LGW(4); SB0;
        PRIO1; mfma16(0, aF1, bK1); PRIO0;
        LGW(0); SB0;
        PRIO1; mfma16(4, aF2, bK1); PRIO0;
        BAR;
        dsA(2, 0, 0, aF1);
    }
    // t=35 (slot 2): final
    {
        loadBk(bK1, 35, 1);
        dsA(2, 1, 0, aF2);
        VMW(4); SB0;                              // Bk0(35) done
        LGW(4); SB0;
        PRIO1; mfma16(0, aF1, bK0); PRIO0;
        dsA(2, 0, 1, aF1);
        LGW(4); SB0;
        PRIO1; mfma16(4, aF2, bK0); PRIO0;
        dsA(2, 1, 1, aF2);
        VMW(0); SB0;                              // Bk1(35) done
        LGW(4); SB0;
        PRIO1; mfma16(0, aF1, bK1); PRIO0;
        LGW(0); SB0;
        PRIO1; mfma16(4, aF2, bK1); PRIO0;
    }

    // epilogue: C/D layout col=lane&15, row=(lane>>4)*4+j
    #pragma unroll
    for (int m = 0; m < 8; ++m)
        #pragma unroll
        for (int n = 0; n < 4; ++n)
            #pragma unroll
            for (int j = 0; j < 4; ++j) {
                int ro = wro + m * 16 + lg * 4 + j;
                int co = n0 + wco + n * 16 + lr;
                out[((size_t)(b * O_ + ro)) * HW_ + co] = acc[m][n][j];
            }
}

extern "C" void kernel_launch(void* const* d_in, const int* in_sizes, int n_in,
                              void* d_out, int out_size, void* d_ws, size_t ws_size,
                              hipStream_t stream) {
    const float* x  = (const float*)d_in[0];
    const float* We = (const float*)d_in[1];
    const float* gw = (const float*)d_in[2];
    float* out = (float*)d_out;

    // ws: part @0 (256KB), gates @262144, Wc @263168 (18.87MB -> 19137536),
    //     xT @19137536 (16*66*66*256*2B = 35.68MB) -> ~54.8MB total
    float*  part  = (float*)d_ws;
    float*  gates = (float*)((char*)d_ws + 262144);
    ushort* Wcomb = (ushort*)((char*)d_ws + 263168);
    ushort* xTp   = (ushort*)((char*)d_ws + 19137536);

    transpose_kernel<<<dim3(64, 16), 256, 0, stream>>>(x, xTp, part);
    gate_kernel<<<16, 256, 0, stream>>>(part, gw, gates);
    combine_kernel<<<O_, 256, 0, stream>>>(We, gates, Wcomb);
    conv_kernel<<<256, 512, 0, stream>>>(xTp, Wcomb, out);
}